// Round 16
// baseline (52.487 us; speedup 1.0000x reference)
//
#include <hip/hip_runtime.h>
#include <hip/hip_fp16.h>
#include <cstdint>

#define BLOCK 256
#define ROWS 128    // rows per block: each thread handles rows (lane, lane+64)
#define NRECU 40    // u32 (half2) per preprocessed PAIR record (160 B)

typedef float v2f __attribute__((ext_vector_type(2)));
typedef float v4f __attribute__((ext_vector_type(4)));
typedef _Float16 h2 __attribute__((ext_vector_type(2)));

__device__ __forceinline__ float exp2s(float x) { return __builtin_amdgcn_exp2f(x); }
__device__ __forceinline__ float log2s(float x) { return __builtin_amdgcn_logf(x); }
__device__ __forceinline__ v2f fma2(v2f a, v2f b, v2f c) { return __builtin_elementwise_fma(a, b, c); }

__device__ __forceinline__ h2 fmah(h2 a, h2 b, h2 c) { return __builtin_elementwise_fma(a, b, c); }
__device__ __forceinline__ h2 maxh(h2 a, h2 b) { return __builtin_elementwise_max(a, b); }
__device__ __forceinline__ h2 minh(h2 a, h2 b) { return __builtin_elementwise_min(a, b); }

union h2u { h2 h; uint32_t u; __half2 hh; };

__device__ __forceinline__ h2 exp2h(h2 x) {
    h2u a; a.h = x;
    h2u r; r.hh = h2exp2(a.hh);   // 2x v_exp_f16
    return r.h;
}
__device__ __forceinline__ h2 splath(float s) {
    const _Float16 v = (_Float16)s;
    return (h2){v, v};
}

#define LN2 0.6931471805599453f
#define L2E 1.4426950408889634f

constexpr int GAS_[76] = {
    0,0,0,0,0,0,0,0,0,0,0,0,0,0,0,0,0,0,0,0,0,0,0,0,0,0,0,0,0,
    1,1,1,1,1,1,1,1,1,1,1,1,1,
    2,2,2,2,2,2,2,2,2,
    3,3,3,
    4,4,4,4,4,4,4,4,4,
    5,5,5,5,5,5,5,5,5,5,5,5,5};
constexpr int CHAN_[76] = {
    0,1,2,3,4,5,6,7,8,9,10,11,12,13,14,15,16,17,18,19,20,21,22,23,24,25,26,27,28,
    0,1,2,17,18,19,20,21,22,25,26,27,28,
    0,1,2,5,6,9,10,13,14,
    0,1,2,
    0,1,2,3,4,7,8,11,12,
    0,1,2,15,16,17,18,19,20,21,22,27,28};

// ---- prep kernel: pair-interleaved HALF2 net records, log2e-scaled ----
// pair p = nets (2p,2p+1), one net per f16 half. u32 indices:
//   [0..7] W1*L2E  [8..11] b1*L2E  [12..27] W2*L2E
//   [28..31] (b2 - sum_i W2[i][o])*L2E  [32..35] W3*L2E  [36] (b3-sumW3)*L2E
// tail at rec+38*NRECU (as float): per channel float4 {W_lw,b_lw,W_iw,b_iw}*L2E
__global__ void __launch_bounds__(128)
prep_kernel(const float* __restrict__ W1, const float* __restrict__ b1,
            const float* __restrict__ W2, const float* __restrict__ b2,
            const float* __restrict__ W3, const float* __restrict__ b3,
            const float* __restrict__ W_lw, const float* __restrict__ b_lw,
            const float* __restrict__ W_iw, const float* __restrict__ b_iw,
            float* __restrict__ rec)
{
    const int p = threadIdx.x;
    if (p < 38) {
        const int nA = 2 * p, nB = 2 * p + 1;
        uint32_t* r = (uint32_t*)rec + p * NRECU;
        auto pack = [](float a, float b) -> uint32_t {
            h2u v; v.h = (h2){(_Float16)a, (_Float16)b};
            return v.u;
        };
        #pragma unroll
        for (int k = 0; k < 8; ++k)
            r[k] = pack(W1[nA * 8 + k] * L2E, W1[nB * 8 + k] * L2E);
        #pragma unroll
        for (int o = 0; o < 4; ++o)
            r[8 + o] = pack(b1[nA * 4 + o] * L2E, b1[nB * 4 + o] * L2E);
        #pragma unroll
        for (int k = 0; k < 16; ++k)
            r[12 + k] = pack(W2[nA * 16 + k] * L2E, W2[nB * 16 + k] * L2E);
        #pragma unroll
        for (int o = 0; o < 4; ++o) {
            float sA = 0.0f, sB = 0.0f;
            #pragma unroll
            for (int i = 0; i < 4; ++i) {
                sA += W2[nA * 16 + i * 4 + o];
                sB += W2[nB * 16 + i * 4 + o];
            }
            r[28 + o] = pack((b2[nA * 4 + o] - sA) * L2E, (b2[nB * 4 + o] - sB) * L2E);
        }
        float s3A = 0.0f, s3B = 0.0f;
        #pragma unroll
        for (int i = 0; i < 4; ++i) {
            r[32 + i] = pack(W3[nA * 4 + i] * L2E, W3[nB * 4 + i] * L2E);
            s3A += W3[nA * 4 + i];
            s3B += W3[nB * 4 + i];
        }
        r[36] = pack((b3[nA] - s3A) * L2E, (b3[nB] - s3B) * L2E);
        r[37] = 0u; r[38] = 0u; r[39] = 0u;
    } else if (p < 38 + 29) {
        const int ch = p - 38;
        float* t = rec + 38 * NRECU + ch * 4;
        t[0] = W_lw[ch] * L2E;
        t[1] = b_lw[ch] * L2E;
        t[2] = W_iw[ch] * L2E;
        t[3] = b_iw[ch] * L2E;
    }
}

// H = elu(a)+1 = max(a+1, 2^min(as,0)), as = a*log2e; packed f16 (1 slot/op).
__device__ __forceinline__ h2 elu_h16(h2 as) {
    return maxh(fmah(as, splath(LN2), splath(1.0f)), exp2h(minh(as, splath(0.0f))));
}

// Run pairs [PS,PE) for TWO rows: dual independent h2 streams (a=row0, b=row1)
// sharing the same wave-uniform weight scalars -> 2x ILP, s_loads amortized.
// tau is v2f per channel: .x=row0, .y=row1.
template<int PS, int PE>
__device__ __forceinline__ void run_pairs2(
    const uint32_t* __restrict__ recU,
    h2 tpxa, h2 tpya, h2 tpxb, h2 tpyb,
    const v2f* cgl2 /* [6], cg*ln2 for {row0,row1} */, v2f* tau)
{
    #pragma unroll
    for (int p = PS; p < PE; ++p) {
        const h2* __restrict__ RP = (const h2*)(recU + p * NRECU);
        h2 H1a[4], H1b[4];
        #pragma unroll
        for (int o = 0; o < 4; ++o) {
            H1a[o] = elu_h16(fmah(tpxa, RP[o], fmah(tpya, RP[4 + o], RP[8 + o])));
            H1b[o] = elu_h16(fmah(tpxb, RP[o], fmah(tpyb, RP[4 + o], RP[8 + o])));
        }
        h2 H2a[4], H2b[4];
        #pragma unroll
        for (int o = 0; o < 4; ++o) {
            h2 aa = RP[28 + o];
            h2 ab = RP[28 + o];
            #pragma unroll
            for (int i = 0; i < 4; ++i) {
                aa = fmah(H1a[i], RP[12 + i * 4 + o], aa);
                ab = fmah(H1b[i], RP[12 + i * 4 + o], ab);
            }
            H2a[o] = elu_h16(aa);
            H2b[o] = elu_h16(ab);
        }
        h2 a3a = RP[36];
        h2 a3b = RP[36];
        #pragma unroll
        for (int i = 0; i < 4; ++i) {
            a3a = fmah(H2a[i], RP[32 + i], a3a);
            a3b = fmah(H2b[i], RP[32 + i], a3b);
        }
        // f32 softplus in log2 units: max(a3,0) + log2(1 + 2^-|a3|)
        const float ax0 = (float)a3a.x, ay0 = (float)a3a.y;
        const float ax1 = (float)a3b.x, ay1 = (float)a3b.y;
        const v2f sp0 = {fmaxf(ax0, 0.0f) + log2s(1.0f + exp2s(-fabsf(ax0))),
                         fmaxf(ax1, 0.0f) + log2s(1.0f + exp2s(-fabsf(ax1)))};
        const v2f sp1 = {fmaxf(ay0, 0.0f) + log2s(1.0f + exp2s(-fabsf(ay0))),
                         fmaxf(ay1, 0.0f) + log2s(1.0f + exp2s(-fabsf(ay1)))};
        tau[CHAN_[2 * p]]     = fma2(sp0, cgl2[GAS_[2 * p]],     tau[CHAN_[2 * p]]);
        tau[CHAN_[2 * p + 1]] = fma2(sp1, cgl2[GAS_[2 * p + 1]], tau[CHAN_[2 * p + 1]]);
    }
}

template<bool EXACT>
__global__ void __launch_bounds__(BLOCK)
od_kernel(const float* __restrict__ t_p,
          const float* __restrict__ comp,
          const float* __restrict__ null_lw,
          const float* __restrict__ null_iw,
          const float* __restrict__ rec,
          float* __restrict__ out, int B)
{
    // single 64-row stage pair (14,848 B) reused for both row-halves:
    // occupancy cap stays 8 blocks/CU; grid 2048 = exactly one round.
    __shared__ float stage[2][64 * 29];

    const int tid  = threadIdx.x;
    const int wave = tid >> 6;
    const int lane = tid & 63;
    const int base = blockIdx.x * ROWS;
    int r0 = base + lane;
    int r1 = base + 64 + lane;
    if (!EXACT) { r0 = r0 < B ? r0 : B - 1; r1 = r1 < B ? r1 : B - 1; }

    const float2 ta = *reinterpret_cast<const float2*>(t_p + (size_t)r0 * 2);
    const float2 tb = *reinterpret_cast<const float2*>(t_p + (size_t)r1 * 2);
    const float4 ca0 = *reinterpret_cast<const float4*>(comp + (size_t)r0 * 8);
    const float2 cb0 = *reinterpret_cast<const float2*>(comp + (size_t)r0 * 8 + 4);
    const float4 ca1 = *reinterpret_cast<const float4*>(comp + (size_t)r1 * 8);
    const float2 cb1 = *reinterpret_cast<const float2*>(comp + (size_t)r1 * 8 + 4);
    const v2f cgl2[6] = {
        {ca0.x * LN2, ca1.x * LN2}, {ca0.y * LN2, ca1.y * LN2},
        {ca0.z * LN2, ca1.z * LN2}, {ca0.w * LN2, ca1.w * LN2},
        {cb0.x * LN2, cb1.x * LN2}, {cb0.y * LN2, cb1.y * LN2}};

    const h2 tpxa = splath(ta.x), tpya = splath(ta.y);
    const h2 tpxb = splath(tb.x), tpyb = splath(tb.y);

    v2f tau[29];
    #pragma unroll
    for (int i = 0; i < 29; ++i) tau[i] = (v2f){0.0f, 0.0f};

    const uint32_t* __restrict__ recU = (const uint32_t*)rec;

    // pair ranges {10,10,9,9}: lighter waves 2,3 do the LDS RMW phases below
    switch (wave) {
        case 0: run_pairs2< 0, 10>(recU, tpxa, tpya, tpxb, tpyb, cgl2, tau); break;
        case 1: run_pairs2<10, 20>(recU, tpxa, tpya, tpxb, tpyb, cgl2, tau); break;
        case 2: run_pairs2<20, 29>(recU, tpxa, tpya, tpxb, tpyb, cgl2, tau); break;
        default: run_pairs2<29, 38>(recU, tpxa, tpya, tpxb, tpyb, cgl2, tau); break;
    }

    const size_t BN = (size_t)B * 29;
    const float* __restrict__ recL = rec + 38 * NRECU;

    // two sequential passes through the same 64-row stage buffers
    #pragma unroll
    for (int pass = 0; pass < 2; ++pass) {
        // stage this half's tau (stride 29 coprime w/ 32 banks: conflict-free)
        if (wave < 2) {
            #pragma unroll
            for (int i = 0; i < 29; ++i)
                stage[wave][lane * 29 + i] = pass ? tau[i].y : tau[i].x;
        }
        __syncthreads();
        if (wave >= 2) {
            float* p = stage[wave - 2];
            #pragma unroll
            for (int i = 0; i < 29; ++i)
                p[lane * 29 + i] += pass ? tau[i].y : tau[i].x;
        }
        __syncthreads();

        const int pbase = base + pass * 64;
        const size_t obase = (size_t)pbase * 29;

        if (EXACT) {
            // vectorized epilogue: ds_read_b128 + 3x nontemporal dwordx4
            const int t4 = tid * 4;
            #pragma unroll
            for (int it = 0; it < 2; ++it) {
                const int idx = t4 + it * (BLOCK * 4);
                if (idx < 64 * 29) {
                    const v4f s0 = *reinterpret_cast<const v4f*>(&stage[0][idx]);
                    const v4f s1 = *reinterpret_cast<const v4f*>(&stage[1][idx]);
                    const v4f v0 = s0 + s1;

                    float o1[4], o2[4];
                    int rr = idx / 29;
                    int cc = idx - rr * 29;
                    #pragma unroll
                    for (int j = 0; j < 4; ++j) {
                        const int grow = pbase + rr;
                        const float nl = null_lw[grow];
                        const float ni = null_iw[grow];
                        const float c6 = comp[(size_t)grow * 8 + 6] * LN2;
                        const float c7 = comp[(size_t)grow * 8 + 7] * LN2;
                        const v4f L = *reinterpret_cast<const v4f*>(recL + cc * 4);
                        const float alw = fmaf(nl, L.x, L.y);
                        const float aiw = fmaf(ni, L.z, L.w);
                        o1[j] = (fmaxf(alw, 0.0f) + log2s(1.0f + exp2s(-fabsf(alw)))) * c6;
                        o2[j] = (fmaxf(aiw, 0.0f) + log2s(1.0f + exp2s(-fabsf(aiw)))) * c7;
                        if (++cc == 29) { cc = 0; ++rr; }
                    }
                    const v4f v1 = {o1[0], o1[1], o1[2], o1[3]};
                    const v4f v2 = {o2[0], o2[1], o2[2], o2[3]};
                    __builtin_nontemporal_store(v0, reinterpret_cast<v4f*>(out + obase + idx));
                    __builtin_nontemporal_store(v1, reinterpret_cast<v4f*>(out + BN + obase + idx));
                    __builtin_nontemporal_store(v2, reinterpret_cast<v4f*>(out + 2 * BN + obase + idx));
                }
            }
        } else {
            int rrem = B - pbase;
            rrem = rrem < 0 ? 0 : (rrem > 64 ? 64 : rrem);
            const int lim = rrem * 29;
            for (int idx = tid; idx < lim; idx += BLOCK) {
                out[obase + idx] = stage[0][idx] + stage[1][idx];
                const int r  = idx / 29;
                const int ch = idx - r * 29;
                const int grow = pbase + r;
                const float nl = null_lw[grow];
                const float ni = null_iw[grow];
                const float c6 = comp[(size_t)grow * 8 + 6] * LN2;
                const float c7 = comp[(size_t)grow * 8 + 7] * LN2;
                const v4f L = *reinterpret_cast<const v4f*>(recL + ch * 4);
                const float alw = fmaf(nl, L.x, L.y);
                const float aiw = fmaf(ni, L.z, L.w);
                out[BN + obase + idx] =
                    (fmaxf(alw, 0.0f) + log2s(1.0f + exp2s(-fabsf(alw)))) * c6;
                out[2 * BN + obase + idx] =
                    (fmaxf(aiw, 0.0f) + log2s(1.0f + exp2s(-fabsf(aiw)))) * c7;
            }
        }
        if (pass == 0) __syncthreads();   // WAR: stage reused next pass
    }
}

extern "C" void kernel_launch(void* const* d_in, const int* in_sizes, int n_in,
                              void* d_out, int out_size, void* d_ws, size_t ws_size,
                              hipStream_t stream) {
    const float* t_p     = (const float*)d_in[0];
    const float* comp    = (const float*)d_in[1];
    const float* null_lw = (const float*)d_in[2];
    const float* null_iw = (const float*)d_in[3];
    const float* W1      = (const float*)d_in[4];
    const float* b1      = (const float*)d_in[5];
    const float* W2      = (const float*)d_in[6];
    const float* b2      = (const float*)d_in[7];
    const float* W3      = (const float*)d_in[8];
    const float* b3      = (const float*)d_in[9];
    const float* W_lw    = (const float*)d_in[10];
    const float* b_lw    = (const float*)d_in[11];
    const float* W_iw    = (const float*)d_in[12];
    const float* b_iw    = (const float*)d_in[13];
    float* out = (float*)d_out;
    float* rec = (float*)d_ws;   // 38*40*4 + 29*4*4 = 6,544 B

    const int B = in_sizes[0] / 2;

    prep_kernel<<<1, 128, 0, stream>>>(W1, b1, W2, b2, W3, b3,
                                       W_lw, b_lw, W_iw, b_iw, rec);

    const int blocks = (B + ROWS - 1) / ROWS;
    if (B % ROWS == 0)
        od_kernel<true><<<blocks, BLOCK, 0, stream>>>(t_p, comp, null_lw, null_iw,
                                                      rec, out, B);
    else
        od_kernel<false><<<blocks, BLOCK, 0, stream>>>(t_p, comp, null_lw, null_iw,
                                                       rec, out, B);
}

// Round 17
// 51.974 us; speedup vs baseline: 1.0099x; 1.0099x over previous
//
#include <hip/hip_runtime.h>
#include <hip/hip_fp16.h>
#include <cstdint>

#define BLOCK 256
#define ROWS 64     // rows per block, 1 row per lane; all 4 waves share the rows
#define NRECU 40    // u32 (half2) per preprocessed PAIR record (160 B)

typedef float v4f __attribute__((ext_vector_type(4)));
typedef _Float16 h2 __attribute__((ext_vector_type(2)));

__device__ __forceinline__ float exp2s(float x) { return __builtin_amdgcn_exp2f(x); }
__device__ __forceinline__ float log2s(float x) { return __builtin_amdgcn_logf(x); }

__device__ __forceinline__ h2 fmah(h2 a, h2 b, h2 c) { return __builtin_elementwise_fma(a, b, c); }
__device__ __forceinline__ h2 maxh(h2 a, h2 b) { return __builtin_elementwise_max(a, b); }
__device__ __forceinline__ h2 minh(h2 a, h2 b) { return __builtin_elementwise_min(a, b); }

union h2u { h2 h; uint32_t u; __half2 hh; };

__device__ __forceinline__ h2 exp2h(h2 x) {
    h2u a; a.h = x;
    h2u r; r.hh = h2exp2(a.hh);   // 2x v_exp_f16
    return r.h;
}
__device__ __forceinline__ h2 splath(float s) {
    const _Float16 v = (_Float16)s;
    return (h2){v, v};
}

#define LN2 0.6931471805599453f
#define L2E 1.4426950408889634f

constexpr int GAS_[76] = {
    0,0,0,0,0,0,0,0,0,0,0,0,0,0,0,0,0,0,0,0,0,0,0,0,0,0,0,0,0,
    1,1,1,1,1,1,1,1,1,1,1,1,1,
    2,2,2,2,2,2,2,2,2,
    3,3,3,
    4,4,4,4,4,4,4,4,4,
    5,5,5,5,5,5,5,5,5,5,5,5,5};
constexpr int CHAN_[76] = {
    0,1,2,3,4,5,6,7,8,9,10,11,12,13,14,15,16,17,18,19,20,21,22,23,24,25,26,27,28,
    0,1,2,17,18,19,20,21,22,25,26,27,28,
    0,1,2,5,6,9,10,13,14,
    0,1,2,
    0,1,2,3,4,7,8,11,12,
    0,1,2,15,16,17,18,19,20,21,22,27,28};

// ---- prep kernel: pair-interleaved HALF2 net records, log2e-scaled ----
// pair p = nets (2p,2p+1), one net per f16 half. u32 indices:
//   [0..7] W1*L2E  [8..11] b1*L2E  [12..27] W2*L2E
//   [28..31] (b2 - sum_i W2[i][o])*L2E  [32..35] W3*L2E  [36] (b3-sumW3)*L2E
// tail at rec+38*NRECU (as float): per channel float4 {W_lw,b_lw,W_iw,b_iw}*L2E
__global__ void __launch_bounds__(128)
prep_kernel(const float* __restrict__ W1, const float* __restrict__ b1,
            const float* __restrict__ W2, const float* __restrict__ b2,
            const float* __restrict__ W3, const float* __restrict__ b3,
            const float* __restrict__ W_lw, const float* __restrict__ b_lw,
            const float* __restrict__ W_iw, const float* __restrict__ b_iw,
            float* __restrict__ rec)
{
    const int p = threadIdx.x;
    if (p < 38) {
        const int nA = 2 * p, nB = 2 * p + 1;
        uint32_t* r = (uint32_t*)rec + p * NRECU;
        auto pack = [](float a, float b) -> uint32_t {
            h2u v; v.h = (h2){(_Float16)a, (_Float16)b};
            return v.u;
        };
        #pragma unroll
        for (int k = 0; k < 8; ++k)
            r[k] = pack(W1[nA * 8 + k] * L2E, W1[nB * 8 + k] * L2E);
        #pragma unroll
        for (int o = 0; o < 4; ++o)
            r[8 + o] = pack(b1[nA * 4 + o] * L2E, b1[nB * 4 + o] * L2E);
        #pragma unroll
        for (int k = 0; k < 16; ++k)
            r[12 + k] = pack(W2[nA * 16 + k] * L2E, W2[nB * 16 + k] * L2E);
        #pragma unroll
        for (int o = 0; o < 4; ++o) {
            float sA = 0.0f, sB = 0.0f;
            #pragma unroll
            for (int i = 0; i < 4; ++i) {
                sA += W2[nA * 16 + i * 4 + o];
                sB += W2[nB * 16 + i * 4 + o];
            }
            r[28 + o] = pack((b2[nA * 4 + o] - sA) * L2E, (b2[nB * 4 + o] - sB) * L2E);
        }
        float s3A = 0.0f, s3B = 0.0f;
        #pragma unroll
        for (int i = 0; i < 4; ++i) {
            r[32 + i] = pack(W3[nA * 4 + i] * L2E, W3[nB * 4 + i] * L2E);
            s3A += W3[nA * 4 + i];
            s3B += W3[nB * 4 + i];
        }
        r[36] = pack((b3[nA] - s3A) * L2E, (b3[nB] - s3B) * L2E);
        r[37] = 0u; r[38] = 0u; r[39] = 0u;
    } else if (p < 38 + 29) {
        const int ch = p - 38;
        float* t = rec + 38 * NRECU + ch * 4;
        t[0] = W_lw[ch] * L2E;
        t[1] = b_lw[ch] * L2E;
        t[2] = W_iw[ch] * L2E;
        t[3] = b_iw[ch] * L2E;
    }
}

// H = elu(a)+1 = max(a+1, 2^min(as,0)), as = a*log2e; packed f16 (1 slot/op).
__device__ __forceinline__ h2 elu_h16(h2 as) {
    return maxh(fmah(as, splath(LN2), splath(1.0f)), exp2h(minh(as, splath(0.0f))));
}

// Run pairs [PS,PE) for one row: layers in packed f16 (one net per half),
// softplus + channel scatter in f32. Compile-time range keeps CHAN_/GAS_
// constexpr (tau in regs) and record offsets wave-uniform scalar loads.
template<int PS, int PE>
__device__ __forceinline__ void run_pairs(
    const uint32_t* __restrict__ recU, h2 tpx2, h2 tpy2,
    const float* cgl2 /* cg * ln2 */, float* tau)
{
    #pragma unroll
    for (int p = PS; p < PE; ++p) {
        const h2* __restrict__ RP = (const h2*)(recU + p * NRECU);
        h2 H1[4];
        #pragma unroll
        for (int o = 0; o < 4; ++o)
            H1[o] = elu_h16(fmah(tpx2, RP[o], fmah(tpy2, RP[4 + o], RP[8 + o])));
        h2 H2[4];
        #pragma unroll
        for (int o = 0; o < 4; ++o) {
            h2 a = RP[28 + o];
            #pragma unroll
            for (int i = 0; i < 4; ++i)
                a = fmah(H1[i], RP[12 + i * 4 + o], a);
            H2[o] = elu_h16(a);
        }
        h2 a3 = RP[36];
        #pragma unroll
        for (int i = 0; i < 4; ++i)
            a3 = fmah(H2[i], RP[32 + i], a3);
        // f32 softplus in log2 units: max(a3,0) + log2(1 + 2^-|a3|)
        const float ax = (float)a3.x;
        const float ay = (float)a3.y;
        const float spx = fmaxf(ax, 0.0f) + log2s(1.0f + exp2s(-fabsf(ax)));
        const float spy = fmaxf(ay, 0.0f) + log2s(1.0f + exp2s(-fabsf(ay)));
        tau[CHAN_[2 * p]]     = fmaf(spx, cgl2[GAS_[2 * p]],     tau[CHAN_[2 * p]]);
        tau[CHAN_[2 * p + 1]] = fmaf(spy, cgl2[GAS_[2 * p + 1]], tau[CHAN_[2 * p + 1]]);
    }
}

template<bool EXACT>
__global__ void __launch_bounds__(BLOCK)
od_kernel(const float* __restrict__ t_p,
          const float* __restrict__ comp,
          const float* __restrict__ null_lw,
          const float* __restrict__ null_iw,
          const float* __restrict__ rec,
          float* __restrict__ out, int B)
{
    // 2 partial tau panels (14,848 B) -> occupancy capped by 32 waves/CU.
    __shared__ float stage[2][ROWS * 29];

    const int tid  = threadIdx.x;
    const int wave = tid >> 6;
    const int lane = tid & 63;
    const int base = blockIdx.x * ROWS;
    const int row  = EXACT ? (base + lane)
                           : ((base + lane < B) ? (base + lane) : (B - 1));

    const float2 tp = *reinterpret_cast<const float2*>(t_p + (size_t)row * 2);
    const float4 ca = *reinterpret_cast<const float4*>(comp + (size_t)row * 8);
    const float2 cb = *reinterpret_cast<const float2*>(comp + (size_t)row * 8 + 4);
    const float cgl2[6] = {ca.x * LN2, ca.y * LN2, ca.z * LN2,
                           ca.w * LN2, cb.x * LN2, cb.y * LN2};

    const h2 tpx2 = splath(tp.x);
    const h2 tpy2 = splath(tp.y);

    float tau[29];
    #pragma unroll
    for (int i = 0; i < 29; ++i) tau[i] = 0.0f;

    const uint32_t* __restrict__ recU = (const uint32_t*)rec;

    // pair ranges {10,10,9,9}: lighter waves 2,3 do the LDS RMW phase below
    switch (wave) {
        case 0: run_pairs< 0, 10>(recU, tpx2, tpy2, cgl2, tau); break;
        case 1: run_pairs<10, 20>(recU, tpx2, tpy2, cgl2, tau); break;
        case 2: run_pairs<20, 29>(recU, tpx2, tpy2, cgl2, tau); break;
        default: run_pairs<29, 38>(recU, tpx2, tpy2, cgl2, tau); break;
    }

    // 2-phase reduction; stride 29 coprime with 32 banks -> conflict-free.
    if (wave < 2) {
        #pragma unroll
        for (int i = 0; i < 29; ++i) stage[wave][lane * 29 + i] = tau[i];
    }
    __syncthreads();
    if (wave >= 2) {
        float* p = stage[wave - 2];
        #pragma unroll
        for (int i = 0; i < 29; ++i) p[lane * 29 + i] += tau[i];
    }
    __syncthreads();

    const size_t obase = (size_t)base * 29;
    const size_t BN = (size_t)B * 29;
    const float* __restrict__ recL = rec + 38 * NRECU;

    if (EXACT) {
        // vectorized epilogue: 4 consecutive dwords per thread per region,
        // ds_read_b128 + 3x nontemporal global_store_dwordx4, fully coalesced.
        const int t4 = tid * 4;
        #pragma unroll
        for (int it = 0; it < 2; ++it) {
            const int idx = t4 + it * (BLOCK * 4);
            if (idx < ROWS * 29) {
                const v4f s0 = *reinterpret_cast<const v4f*>(&stage[0][idx]);
                const v4f s1 = *reinterpret_cast<const v4f*>(&stage[1][idx]);
                const v4f v0 = s0 + s1;

                float o1[4], o2[4];
                int rr = idx / 29;
                int cc = idx - rr * 29;
                #pragma unroll
                for (int j = 0; j < 4; ++j) {
                    const int grow = base + rr;
                    const float nl = null_lw[grow];
                    const float ni = null_iw[grow];
                    const float c6 = comp[(size_t)grow * 8 + 6] * LN2;
                    const float c7 = comp[(size_t)grow * 8 + 7] * LN2;
                    const v4f L = *reinterpret_cast<const v4f*>(recL + cc * 4);
                    const float alw = fmaf(nl, L.x, L.y);
                    const float aiw = fmaf(ni, L.z, L.w);
                    o1[j] = (fmaxf(alw, 0.0f) + log2s(1.0f + exp2s(-fabsf(alw)))) * c6;
                    o2[j] = (fmaxf(aiw, 0.0f) + log2s(1.0f + exp2s(-fabsf(aiw)))) * c7;
                    if (++cc == 29) { cc = 0; ++rr; }
                }
                const v4f v1 = {o1[0], o1[1], o1[2], o1[3]};
                const v4f v2 = {o2[0], o2[1], o2[2], o2[3]};
                __builtin_nontemporal_store(v0, reinterpret_cast<v4f*>(out + obase + idx));
                __builtin_nontemporal_store(v1, reinterpret_cast<v4f*>(out + BN + obase + idx));
                __builtin_nontemporal_store(v2, reinterpret_cast<v4f*>(out + 2 * BN + obase + idx));
            }
        }
    } else {
        const int rrem0 = B - base;
        const int rrem = rrem0 < 0 ? 0 : (rrem0 > ROWS ? ROWS : rrem0);
        const int lim = rrem * 29;
        for (int idx = tid; idx < lim; idx += BLOCK) {
            out[obase + idx] = stage[0][idx] + stage[1][idx];
            const int r  = idx / 29;
            const int ch = idx - r * 29;
            const int grow = base + r;
            const float nl = null_lw[grow];
            const float ni = null_iw[grow];
            const float c6 = comp[(size_t)grow * 8 + 6] * LN2;
            const float c7 = comp[(size_t)grow * 8 + 7] * LN2;
            const v4f L = *reinterpret_cast<const v4f*>(recL + ch * 4);
            const float alw = fmaf(nl, L.x, L.y);
            const float aiw = fmaf(ni, L.z, L.w);
            out[BN + obase + idx] =
                (fmaxf(alw, 0.0f) + log2s(1.0f + exp2s(-fabsf(alw)))) * c6;
            out[2 * BN + obase + idx] =
                (fmaxf(aiw, 0.0f) + log2s(1.0f + exp2s(-fabsf(aiw)))) * c7;
        }
    }
}

extern "C" void kernel_launch(void* const* d_in, const int* in_sizes, int n_in,
                              void* d_out, int out_size, void* d_ws, size_t ws_size,
                              hipStream_t stream) {
    const float* t_p     = (const float*)d_in[0];
    const float* comp    = (const float*)d_in[1];
    const float* null_lw = (const float*)d_in[2];
    const float* null_iw = (const float*)d_in[3];
    const float* W1      = (const float*)d_in[4];
    const float* b1      = (const float*)d_in[5];
    const float* W2      = (const float*)d_in[6];
    const float* b2      = (const float*)d_in[7];
    const float* W3      = (const float*)d_in[8];
    const float* b3      = (const float*)d_in[9];
    const float* W_lw    = (const float*)d_in[10];
    const float* b_lw    = (const float*)d_in[11];
    const float* W_iw    = (const float*)d_in[12];
    const float* b_iw    = (const float*)d_in[13];
    float* out = (float*)d_out;
    float* rec = (float*)d_ws;   // 38*40*4 + 29*4*4 = 6,544 B

    const int B = in_sizes[0] / 2;

    prep_kernel<<<1, 128, 0, stream>>>(W1, b1, W2, b2, W3, b3,
                                       W_lw, b_lw, W_iw, b_iw, rec);

    const int blocks = (B + ROWS - 1) / ROWS;
    if (B % ROWS == 0)
        od_kernel<true><<<blocks, BLOCK, 0, stream>>>(t_p, comp, null_lw, null_iw,
                                                      rec, out, B);
    else
        od_kernel<false><<<blocks, BLOCK, 0, stream>>>(t_p, comp, null_lw, null_iw,
                                                       rec, out, B);
}